// Round 7
// baseline (372.305 us; speedup 1.0000x reference)
//
#include <hip/hip_runtime.h>
#include <hip/hip_bf16.h>
#include <cstdint>
#include <cstddef>

// Problem dims (fixed)
#define BB 16
#define LL 2048
#define MM (BB * LL)   // 32768 rows
#define KK 1024        // inner dim
#define HH 1024        // hidden per gate

typedef __attribute__((ext_vector_type(8))) short bf16x8;
typedef __attribute__((ext_vector_type(4))) float f32x4;

// ---------- fp32 -> bf16 (RNE) ----------
__device__ __forceinline__ unsigned short f2bf(float f) {
    unsigned u = __builtin_bit_cast(unsigned, f);
    u += 0x7fffu + ((u >> 16) & 1u);
    return (unsigned short)(u >> 16);
}

__global__ void cvt_f32_to_bf16(const float* __restrict__ in,
                                unsigned short* __restrict__ out, int n8) {
    int i = blockIdx.x * blockDim.x + threadIdx.x;
    if (i >= n8) return;
    const float4* p = reinterpret_cast<const float4*>(in) + (size_t)i * 2;
    float4 v0 = p[0];
    float4 v1 = p[1];
    union { unsigned short us[8]; uint4 v; } o;
    o.us[0] = f2bf(v0.x); o.us[1] = f2bf(v0.y);
    o.us[2] = f2bf(v0.z); o.us[3] = f2bf(v0.w);
    o.us[4] = f2bf(v1.x); o.us[5] = f2bf(v1.y);
    o.us[6] = f2bf(v1.z); o.us[7] = f2bf(v1.w);
    reinterpret_cast<uint4*>(out)[i] = o.v;
}

// ---------- mask scan ----------
__global__ __launch_bounds__(1024) void scan_mask(const int* __restrict__ mask,
                                                  int* __restrict__ rows,
                                                  int* __restrict__ Na) {
    __shared__ int psum[1024];
    const int t = threadIdx.x;
    const int base = t * 32;
    int m[32];
    int cnt = 0;
#pragma unroll
    for (int i = 0; i < 32; ++i) { m[i] = mask[base + i]; cnt += (m[i] != 0); }
    psum[t] = cnt;
    __syncthreads();
    for (int off = 1; off < 1024; off <<= 1) {
        int v = (t >= off) ? psum[t - off] : 0;
        __syncthreads();
        psum[t] += v;
        __syncthreads();
    }
    int offset = psum[t] - cnt;
#pragma unroll
    for (int i = 0; i < 32; ++i) {
        if (m[i]) rows[offset++] = base + i;
    }
    if (t == 1023) *Na = psum[1023];
}

// ---------- gather active rows of x, f32 -> bf16 ----------
__global__ __launch_bounds__(256) void gather_cvt(const float* __restrict__ x,
                                                  const int* __restrict__ rows,
                                                  const int* __restrict__ Na,
                                                  unsigned short* __restrict__ xbf) {
    const int j = blockIdx.x;
    if (j >= *Na) return;
    const int r = rows[j];
    const float4 v = reinterpret_cast<const float4*>(x + (size_t)r * KK)[threadIdx.x];
    ushort4 o;
    o.x = f2bf(v.x); o.y = f2bf(v.y); o.z = f2bf(v.z); o.w = f2bf(v.w);
    reinterpret_cast<ushort4*>(xbf + (size_t)j * KK)[threadIdx.x] = o;
}

// ---------- exact zeros for masked-out output rows ----------
__global__ __launch_bounds__(256) void zero_masked(const int* __restrict__ mask,
                                                   float* __restrict__ out) {
    const int m = blockIdx.x;
    if (mask[m] != 0) return;
    const int bb = m >> 11;
    const int ll = m & 2047;
    float4 z = {0.f, 0.f, 0.f, 0.f};
    reinterpret_cast<float4*>(out + ((size_t)ll * BB + bb) * HH)[threadIdx.x] = z;
}

// ---------- async global->LDS, 16B per lane ----------
__device__ __forceinline__ void gload16(const unsigned short* g, unsigned short* l) {
    __builtin_amdgcn_global_load_lds(
        (const __attribute__((address_space(1))) unsigned int*)g,
        (__attribute__((address_space(3))) unsigned int*)l,
        16, 0, 0);
}

#define WAITVM10 asm volatile("s_waitcnt vmcnt(10)" ::: "memory")
#define WAITVM5  asm volatile("s_waitcnt vmcnt(5)" ::: "memory")
#define WAITVM0  asm volatile("s_waitcnt vmcnt(0)" ::: "memory")
#define WAITLG0  asm volatile("s_waitcnt lgkmcnt(0)" ::: "memory")
#define SB       __builtin_amdgcn_sched_barrier(0)
#define BAR      __builtin_amdgcn_s_barrier()

// ---------- fused GEMM + GRU gating, 3-deep ring, counted vmcnt ----------
// BM=128, BN=64 x 3 gates, BK=32, 256 threads (4 waves, 2M x 2N).
// Ring of 3 buffers x 10240 shorts (20KB) = 60KB -> 2 blocks/CU.
// Buffer layout (shorts): A0[0,2048) A1[2048,4096) B0 B1 B2 (2048 each).
// Swizzle (64B rows, 4 slots of 16B): slot s at row r holds k-chunk s^((r>>1)&3)
//   -> quarter-wave's 8 same-parity rows spread over all 4 slots = 2-way (free).
// Staged via linear gload dest + inverse-swizzled global source (rule #21).
// Per-iter ledger (5 loads/tile/wave): outstanding {kt,kt+1,kt+2}=15.
//   vmcnt(10) -> BAR : tile kt landed collectively (leaves 10).
//   COMPUTE(kt) ; lgkmcnt(0) -> BAR : all waves' reads of buf kt returned.
//   STAGE(kt+3 -> buf kt%3) : safe WAR (writes land only after that BAR).
// Drain (peel): vmcnt(5) then vmcnt(0) for the last two tiles only.
template <int MODE>
__global__ __launch_bounds__(256, 2) void gru_layer(
    const unsigned short* __restrict__ A,
    const unsigned short* __restrict__ W,
    const float* __restrict__ b_ih,
    const float* __restrict__ b_hh,
    const int* __restrict__ rows,
    const int* __restrict__ Na_p,
    unsigned short* __restrict__ out_bf,
    float* __restrict__ out_f) {
    __shared__ unsigned short lds[3 * 10240];  // 61440 B

    const int Na = *Na_p;
    const int m0 = blockIdx.x * 128;
    if (m0 >= Na) return;
    const int n0 = blockIdx.y * 64;

    const int tid  = threadIdx.x;
    const int lane = tid & 63;
    const int wid  = tid >> 6;
    const int wr   = wid >> 1;  // 0..1
    const int wc   = wid & 1;   // 0..1

    // --- staging: thread t -> unit-linear slot t*16B = (row t/4, slot t&3) ---
    const int trow = tid >> 2;                               // 0..63 within unit
    const int tcol = ((tid & 3) ^ ((trow >> 1) & 3)) * 8;    // inverse-swizzled k
    int r0 = m0 + trow;        if (r0 >= Na) r0 = Na - 1;
    int r1 = m0 + 64 + trow;   if (r1 >= Na) r1 = Na - 1;
    const unsigned short* a0 = A + (size_t)r0 * KK + tcol;
    const unsigned short* a1 = A + (size_t)r1 * KK + tcol;
    const unsigned short* b0 = W + (size_t)(0 * HH + n0 + trow) * KK + tcol;
    const unsigned short* b1 = W + (size_t)(1 * HH + n0 + trow) * KK + tcol;
    const unsigned short* b2 = W + (size_t)(2 * HH + n0 + trow) * KK + tcol;

#define STAGE(kt, Lbase) do {                                    \
        const int _o = (kt) * 32;                                \
        unsigned short* _L = (Lbase) + wid * 512;                \
        gload16(a0 + _o, _L + 0 * 2048);                         \
        gload16(a1 + _o, _L + 1 * 2048);                         \
        gload16(b0 + _o, _L + 2 * 2048);                         \
        gload16(b1 + _o, _L + 3 * 2048);                         \
        gload16(b2 + _o, _L + 4 * 2048);                         \
    } while (0)

    // --- read offsets: lane l, row base+l15, k-chunk c=l>>4 at slot c^((row>>1)&3).
    //     (row>>1)&3 == (lane>>1)&3 because row bases are multiples of 16.
    const int l15 = lane & 15;
    const int akp = (((lane >> 4) ^ (lane >> 1)) & 3) << 3;   // shorts
    int aoff[4], boff[2];
#pragma unroll
    for (int mf = 0; mf < 4; ++mf)
        aoff[mf] = (wr * 64 + mf * 16 + l15) * 32 + akp;
#pragma unroll
    for (int nf = 0; nf < 2; ++nf)
        boff[nf] = 4096 + (wc * 32 + nf * 16 + l15) * 32 + akp;

    f32x4 accr[4][2] = {};
    f32x4 accz[4][2] = {};
    f32x4 accn[4][2] = {};

#define COMPUTE(Lp) do {                                                          \
        bf16x8 af[4];                                                             \
        _Pragma("unroll") for (int mf = 0; mf < 4; ++mf)                          \
            af[mf] = *reinterpret_cast<const bf16x8*>(&(Lp)[aoff[mf]]);           \
        _Pragma("unroll") for (int nf = 0; nf < 2; ++nf) {                        \
            bf16x8 br  = *reinterpret_cast<const bf16x8*>(&(Lp)[boff[nf]]);       \
            bf16x8 bz  = *reinterpret_cast<const bf16x8*>(&(Lp)[boff[nf] + 2048]);\
            bf16x8 bnn = *reinterpret_cast<const bf16x8*>(&(Lp)[boff[nf] + 4096]);\
            __builtin_amdgcn_s_setprio(1);                                        \
            _Pragma("unroll") for (int mf = 0; mf < 4; ++mf) {                    \
                accr[mf][nf] = __builtin_amdgcn_mfma_f32_16x16x32_bf16(           \
                    af[mf], br,  accr[mf][nf], 0, 0, 0);                          \
                accz[mf][nf] = __builtin_amdgcn_mfma_f32_16x16x32_bf16(           \
                    af[mf], bz,  accz[mf][nf], 0, 0, 0);                          \
                accn[mf][nf] = __builtin_amdgcn_mfma_f32_16x16x32_bf16(           \
                    af[mf], bnn, accn[mf][nf], 0, 0, 0);                          \
            }                                                                     \
            __builtin_amdgcn_s_setprio(0);                                        \
        }                                                                         \
    } while (0)

    // prologue: stage tiles 0,1,2 into bufs 0,1,2 (15 loads/wave outstanding)
    STAGE(0, &lds[0]);
    STAGE(1, &lds[10240]);
    STAGE(2, &lds[20480]);

    int cur = 0;  // byte.. short offset of current buffer / 10240
    unsigned short* Lc = &lds[0];
#pragma unroll 1
    for (int kt = 0; kt < 29; ++kt) {
        WAITVM10; BAR; SB;       // tile kt landed everywhere (10 newer in flight)
        COMPUTE(Lc);
        WAITLG0; BAR; SB;        // all waves' reads of this buffer returned
        STAGE(kt + 3, Lc);       // recycle buf (kt%3) for tile kt+3
        cur = (cur == 2) ? 0 : cur + 1;
        Lc = &lds[cur * 10240];
    }
    // ---- drain: tiles 29,30,31 (no more staging) ----
    WAITVM10; BAR; SB;           // tile 29 (10 left: tiles 30,31)
    COMPUTE(Lc);
    cur = (cur == 2) ? 0 : cur + 1; Lc = &lds[cur * 10240];
    WAITVM5; BAR; SB;            // tile 30
    COMPUTE(Lc);
    cur = (cur == 2) ? 0 : cur + 1; Lc = &lds[cur * 10240];
    WAITVM0; BAR; SB;            // tile 31
    COMPUTE(Lc);

    // --- epilogue: gating; C/D layout col = lane&15, row = (lane>>4)*4 + j ---
#pragma unroll
    for (int nf = 0; nf < 2; ++nf) {
        const int col = n0 + wc * 32 + nf * 16 + l15;
        const float br_b = b_ih[col] + b_hh[col];
        const float bz_b = b_ih[HH + col] + b_hh[HH + col];
        const float bn_i = b_ih[2 * HH + col];
        const float bn_h = b_hh[2 * HH + col];
#pragma unroll
        for (int mf = 0; mf < 4; ++mf) {
#pragma unroll
            for (int j = 0; j < 4; ++j) {
                const int row = m0 + wr * 64 + mf * 16 + (lane >> 4) * 4 + j;
                if (row >= Na) continue;
                const float r = 1.f / (1.f + __expf(-(accr[mf][nf][j] + br_b)));
                const float z = 1.f / (1.f + __expf(-(accz[mf][nf][j] + bz_b)));
                const float n = tanhf(accn[mf][nf][j] + bn_i + r * bn_h);
                const float h = (1.f - z) * n;
                if (MODE == 0) {
                    out_bf[(size_t)row * HH + col] = f2bf(h);
                } else {
                    const int orig = rows[row];
                    const int bb = orig >> 11;
                    const int ll = orig & 2047;
                    out_f[((size_t)ll * BB + bb) * HH + col] = h;
                }
            }
        }
    }
#undef STAGE
#undef COMPUTE
}

extern "C" void kernel_launch(void* const* d_in, const int* in_sizes, int n_in,
                              void* d_out, int out_size, void* d_ws, size_t ws_size,
                              hipStream_t stream) {
    const float* x   = (const float*)d_in[0];
    const int*   msk = (const int*)d_in[1];
    const float* W0  = (const float*)d_in[2];
    const float* bi0 = (const float*)d_in[4];
    const float* bh0 = (const float*)d_in[5];
    const float* W1  = (const float*)d_in[6];
    const float* bi1 = (const float*)d_in[8];
    const float* bh1 = (const float*)d_in[9];
    float* out = (float*)d_out;

    char* ws = (char*)d_ws;
    unsigned short* xbf  = (unsigned short*)ws;                  // 67,108,864 B (worst case)
    unsigned short* h1bf = (unsigned short*)(ws + 67108864);     // 67,108,864 B (worst case)
    unsigned short* w0bf = (unsigned short*)(ws + 134217728);    //  6,291,456 B
    unsigned short* w1bf = (unsigned short*)(ws + 140509184);    //  6,291,456 B
    int* rows = (int*)(ws + 146800640);                          //    131,072 B
    int* Na   = (int*)(ws + 146931712);                          //          4 B

    scan_mask<<<1, 1024, 0, stream>>>(msk, rows, Na);

    cvt_f32_to_bf16<<<1536, 256, 0, stream>>>(W0, w0bf, 3 * HH * KK / 8);
    cvt_f32_to_bf16<<<1536, 256, 0, stream>>>(W1, w1bf, 3 * HH * KK / 8);

    zero_masked<<<MM, 256, 0, stream>>>(msk, out);
    gather_cvt<<<MM, 256, 0, stream>>>(x, rows, Na, xbf);

    dim3 grid(MM / 128, HH / 64);  // (256, 16) worst case; blocks past Na exit
    gru_layer<0><<<grid, 256, 0, stream>>>(xbf, w0bf, bi0, bh0, rows, Na, h1bf, nullptr);
    gru_layer<1><<<grid, 256, 0, stream>>>(h1bf, w1bf, bi1, bh1, rows, Na, nullptr, out);
}

// Round 8
// 348.617 us; speedup vs baseline: 1.0679x; 1.0679x over previous
//
#include <hip/hip_runtime.h>
#include <hip/hip_bf16.h>
#include <cstdint>
#include <cstddef>

// Problem dims (fixed)
#define BB 16
#define LL 2048
#define MM (BB * LL)   // 32768 rows
#define KK 1024        // inner dim
#define HH 1024        // hidden per gate

typedef __attribute__((ext_vector_type(8))) short bf16x8;
typedef __attribute__((ext_vector_type(4))) float f32x4;

// ---------- fp32 -> bf16 (RNE) ----------
__device__ __forceinline__ unsigned short f2bf(float f) {
    unsigned u = __builtin_bit_cast(unsigned, f);
    u += 0x7fffu + ((u >> 16) & 1u);
    return (unsigned short)(u >> 16);
}

__global__ void cvt_f32_to_bf16(const float* __restrict__ in,
                                unsigned short* __restrict__ out, int n8) {
    int i = blockIdx.x * blockDim.x + threadIdx.x;
    if (i >= n8) return;
    const float4* p = reinterpret_cast<const float4*>(in) + (size_t)i * 2;
    float4 v0 = p[0];
    float4 v1 = p[1];
    union { unsigned short us[8]; uint4 v; } o;
    o.us[0] = f2bf(v0.x); o.us[1] = f2bf(v0.y);
    o.us[2] = f2bf(v0.z); o.us[3] = f2bf(v0.w);
    o.us[4] = f2bf(v1.x); o.us[5] = f2bf(v1.y);
    o.us[6] = f2bf(v1.z); o.us[7] = f2bf(v1.w);
    reinterpret_cast<uint4*>(out)[i] = o.v;
}

// ---------- mask scan ----------
__global__ __launch_bounds__(1024) void scan_mask(const int* __restrict__ mask,
                                                  int* __restrict__ rows,
                                                  int* __restrict__ Na) {
    __shared__ int psum[1024];
    const int t = threadIdx.x;
    const int base = t * 32;
    int m[32];
    int cnt = 0;
#pragma unroll
    for (int i = 0; i < 32; ++i) { m[i] = mask[base + i]; cnt += (m[i] != 0); }
    psum[t] = cnt;
    __syncthreads();
    for (int off = 1; off < 1024; off <<= 1) {
        int v = (t >= off) ? psum[t - off] : 0;
        __syncthreads();
        psum[t] += v;
        __syncthreads();
    }
    int offset = psum[t] - cnt;
#pragma unroll
    for (int i = 0; i < 32; ++i) {
        if (m[i]) rows[offset++] = base + i;
    }
    if (t == 1023) *Na = psum[1023];
}

// ---------- gather active rows of x, f32 -> bf16 ----------
__global__ __launch_bounds__(256) void gather_cvt(const float* __restrict__ x,
                                                  const int* __restrict__ rows,
                                                  const int* __restrict__ Na,
                                                  unsigned short* __restrict__ xbf) {
    const int j = blockIdx.x;
    if (j >= *Na) return;
    const int r = rows[j];
    const float4 v = reinterpret_cast<const float4*>(x + (size_t)r * KK)[threadIdx.x];
    ushort4 o;
    o.x = f2bf(v.x); o.y = f2bf(v.y); o.z = f2bf(v.z); o.w = f2bf(v.w);
    reinterpret_cast<ushort4*>(xbf + (size_t)j * KK)[threadIdx.x] = o;
}

// ---------- exact zeros for masked-out output rows ----------
__global__ __launch_bounds__(256) void zero_masked(const int* __restrict__ mask,
                                                   float* __restrict__ out) {
    const int m = blockIdx.x;
    if (mask[m] != 0) return;
    const int bb = m >> 11;
    const int ll = m & 2047;
    float4 z = {0.f, 0.f, 0.f, 0.f};
    reinterpret_cast<float4*>(out + ((size_t)ll * BB + bb) * HH)[threadIdx.x] = z;
}

// ---------- async global->LDS, 16B per lane ----------
__device__ __forceinline__ void gload16(const unsigned short* g, unsigned short* l) {
    __builtin_amdgcn_global_load_lds(
        (const __attribute__((address_space(1))) unsigned int*)g,
        (__attribute__((address_space(3))) unsigned int*)l,
        16, 0, 0);
}

#define WAITVM0  asm volatile("s_waitcnt vmcnt(0)" ::: "memory")
#define SB       __builtin_amdgcn_sched_barrier(0)
#define BAR      __builtin_amdgcn_s_barrier()

// ---------- fused GEMM + GRU gating: R6 2-phase dbuf + fixed swizzle + occ=3 ----------
// BM=128, BN=64 x 3 gates, BK=32, 256 threads (4 waves, 2M x 2N).
// 2 buffers x 10240 shorts (20KB) = 40KB LDS.
// Swizzle (64B rows, 4 slots of 16B): slot s of row r holds k-chunk s^((r>>1)&3)
//   -> quarter-wave's 8 same-parity rows spread over 4 slots = 2-way (free);
//   verified conflict-free in R7 (SQ_LDS_BANK_CONFLICT = 0).
// Staged via linear gload dest + inverse-swizzled global source (rule #21).
// Occupancy: acc = 96 AGPRs is fixed; __launch_bounds__(256,3) caps arch VGPRs
// so total/wave <= ~168 -> 3 waves/SIMD (12 waves/CU) -> TLP hides the per-tile
// vmcnt(0) drain (the m97 mechanism). Two structure-deepening attempts (R5,R7)
// lost to this simple loop; occupancy, not pipeline depth, is the binding limit.
template <int MODE>
__global__ __launch_bounds__(256, 3) void gru_layer(
    const unsigned short* __restrict__ A,
    const unsigned short* __restrict__ W,
    const float* __restrict__ b_ih,
    const float* __restrict__ b_hh,
    const int* __restrict__ rows,
    const int* __restrict__ Na_p,
    unsigned short* __restrict__ out_bf,
    float* __restrict__ out_f) {
    __shared__ unsigned short lds[2][10240];  // 40960 B

    const int Na = *Na_p;
    const int m0 = blockIdx.x * 128;
    if (m0 >= Na) return;
    const int n0 = blockIdx.y * 64;

    const int tid  = threadIdx.x;
    const int lane = tid & 63;
    const int wid  = tid >> 6;
    const int wr   = wid >> 1;  // 0..1
    const int wc   = wid & 1;   // 0..1

    // --- staging: thread t -> unit-linear slot t*16B = (row t/4, slot t&3) ---
    const int trow = tid >> 2;                               // 0..63 within unit
    const int tcol = ((tid & 3) ^ ((trow >> 1) & 3)) * 8;    // inverse-swizzled k
    int r0 = m0 + trow;        if (r0 >= Na) r0 = Na - 1;
    int r1 = m0 + 64 + trow;   if (r1 >= Na) r1 = Na - 1;
    const unsigned short* a0 = A + (size_t)r0 * KK + tcol;
    const unsigned short* a1 = A + (size_t)r1 * KK + tcol;
    const unsigned short* b0 = W + (size_t)(0 * HH + n0 + trow) * KK + tcol;
    const unsigned short* b1 = W + (size_t)(1 * HH + n0 + trow) * KK + tcol;
    const unsigned short* b2 = W + (size_t)(2 * HH + n0 + trow) * KK + tcol;

#define STAGE(kt, c) do {                                        \
        const int _o = (kt) * 32;                                \
        unsigned short* _L = &lds[(c)][wid * 512];               \
        gload16(a0 + _o, _L + 0 * 2048);                         \
        gload16(a1 + _o, _L + 1 * 2048);                         \
        gload16(b0 + _o, _L + 2 * 2048);                         \
        gload16(b1 + _o, _L + 3 * 2048);                         \
        gload16(b2 + _o, _L + 4 * 2048);                         \
    } while (0)

    // --- read offsets: lane l, row base+l15, k-chunk c=l>>4 at slot c^((row>>1)&3);
    //     (row>>1)&3 == (lane>>1)&3 because row bases are multiples of 16.
    const int l15 = lane & 15;
    const int akp = (((lane >> 4) ^ (lane >> 1)) & 3) << 3;   // shorts
    int aoff[4], boff[2];
#pragma unroll
    for (int mf = 0; mf < 4; ++mf)
        aoff[mf] = (wr * 64 + mf * 16 + l15) * 32 + akp;
#pragma unroll
    for (int nf = 0; nf < 2; ++nf)
        boff[nf] = 4096 + (wc * 32 + nf * 16 + l15) * 32 + akp;

    f32x4 accr[4][2] = {};
    f32x4 accz[4][2] = {};
    f32x4 accn[4][2] = {};

#define COMPUTE(Lp) do {                                                          \
        bf16x8 af[4];                                                             \
        _Pragma("unroll") for (int mf = 0; mf < 4; ++mf)                          \
            af[mf] = *reinterpret_cast<const bf16x8*>(&(Lp)[aoff[mf]]);           \
        _Pragma("unroll") for (int nf = 0; nf < 2; ++nf) {                        \
            bf16x8 br  = *reinterpret_cast<const bf16x8*>(&(Lp)[boff[nf]]);       \
            bf16x8 bz  = *reinterpret_cast<const bf16x8*>(&(Lp)[boff[nf] + 2048]);\
            bf16x8 bnn = *reinterpret_cast<const bf16x8*>(&(Lp)[boff[nf] + 4096]);\
            __builtin_amdgcn_s_setprio(1);                                        \
            _Pragma("unroll") for (int mf = 0; mf < 4; ++mf) {                    \
                accr[mf][nf] = __builtin_amdgcn_mfma_f32_16x16x32_bf16(           \
                    af[mf], br,  accr[mf][nf], 0, 0, 0);                          \
                accz[mf][nf] = __builtin_amdgcn_mfma_f32_16x16x32_bf16(           \
                    af[mf], bz,  accz[mf][nf], 0, 0, 0);                          \
                accn[mf][nf] = __builtin_amdgcn_mfma_f32_16x16x32_bf16(           \
                    af[mf], bnn, accn[mf][nf], 0, 0, 0);                          \
            }                                                                     \
            __builtin_amdgcn_s_setprio(0);                                        \
        }                                                                         \
    } while (0)

    // prologue: stage tile 0, drain, barrier
    STAGE(0, 0);
    WAITVM0; BAR; SB;

    int cur = 0;
#pragma unroll 1
    for (int kt = 0; kt < 31; ++kt) {
        STAGE(kt + 1, cur ^ 1);          // issue next-tile loads FIRST
        const unsigned short* L = &lds[cur][0];
        COMPUTE(L);                       // ds_read + MFMA hide the load latency
        WAITVM0; BAR; SB;                 // drain after compute, once per tile
        cur ^= 1;
    }
    {   // peeled last tile: no staging
        const unsigned short* L = &lds[cur][0];
        COMPUTE(L);
    }

    // --- epilogue: gating; C/D layout col = lane&15, row = (lane>>4)*4 + j ---
#pragma unroll
    for (int nf = 0; nf < 2; ++nf) {
        const int col = n0 + wc * 32 + nf * 16 + l15;
        const float br_b = b_ih[col] + b_hh[col];
        const float bz_b = b_ih[HH + col] + b_hh[HH + col];
        const float bn_i = b_ih[2 * HH + col];
        const float bn_h = b_hh[2 * HH + col];
#pragma unroll
        for (int mf = 0; mf < 4; ++mf) {
#pragma unroll
            for (int j = 0; j < 4; ++j) {
                const int row = m0 + wr * 64 + mf * 16 + (lane >> 4) * 4 + j;
                if (row >= Na) continue;
                const float r = 1.f / (1.f + __expf(-(accr[mf][nf][j] + br_b)));
                const float z = 1.f / (1.f + __expf(-(accz[mf][nf][j] + bz_b)));
                const float n = tanhf(accn[mf][nf][j] + bn_i + r * bn_h);
                const float h = (1.f - z) * n;
                if (MODE == 0) {
                    out_bf[(size_t)row * HH + col] = f2bf(h);
                } else {
                    const int orig = rows[row];
                    const int bb = orig >> 11;
                    const int ll = orig & 2047;
                    out_f[((size_t)ll * BB + bb) * HH + col] = h;
                }
            }
        }
    }
#undef STAGE
#undef COMPUTE
}

extern "C" void kernel_launch(void* const* d_in, const int* in_sizes, int n_in,
                              void* d_out, int out_size, void* d_ws, size_t ws_size,
                              hipStream_t stream) {
    const float* x   = (const float*)d_in[0];
    const int*   msk = (const int*)d_in[1];
    const float* W0  = (const float*)d_in[2];
    const float* bi0 = (const float*)d_in[4];
    const float* bh0 = (const float*)d_in[5];
    const float* W1  = (const float*)d_in[6];
    const float* bi1 = (const float*)d_in[8];
    const float* bh1 = (const float*)d_in[9];
    float* out = (float*)d_out;

    char* ws = (char*)d_ws;
    unsigned short* xbf  = (unsigned short*)ws;                  // 67,108,864 B (worst case)
    unsigned short* h1bf = (unsigned short*)(ws + 67108864);     // 67,108,864 B (worst case)
    unsigned short* w0bf = (unsigned short*)(ws + 134217728);    //  6,291,456 B
    unsigned short* w1bf = (unsigned short*)(ws + 140509184);    //  6,291,456 B
    int* rows = (int*)(ws + 146800640);                          //    131,072 B
    int* Na   = (int*)(ws + 146931712);                          //          4 B

    scan_mask<<<1, 1024, 0, stream>>>(msk, rows, Na);

    cvt_f32_to_bf16<<<1536, 256, 0, stream>>>(W0, w0bf, 3 * HH * KK / 8);
    cvt_f32_to_bf16<<<1536, 256, 0, stream>>>(W1, w1bf, 3 * HH * KK / 8);

    zero_masked<<<MM, 256, 0, stream>>>(msk, out);
    gather_cvt<<<MM, 256, 0, stream>>>(x, rows, Na, xbf);

    dim3 grid(MM / 128, HH / 64);  // (256, 16) worst case; blocks past Na exit
    gru_layer<0><<<grid, 256, 0, stream>>>(xbf, w0bf, bi0, bh0, rows, Na, h1bf, nullptr);
    gru_layer<1><<<grid, 256, 0, stream>>>(h1bf, w1bf, bi1, bh1, rows, Na, nullptr, out);
}